// Round 14
// baseline (140.887 us; speedup 1.0000x reference)
//
#include <hip/hip_runtime.h>
#include <hip/hip_bf16.h>
#include <hip/hip_fp16.h>
#include <math.h>

#define NF 256    // input features
#define NO 64     // heads*c1 = 8*8
#define NHEAD 8
#define NEG_SLOPE 0.2f
#define BKT 128   // nodes per dst-bucket (d>>7); d_local = 7 bits
#define NBLK 256  // edge-chunk blocks for binning
#define RCAP 8192 // LDS record capacity in k_csr

__device__ __forceinline__ float lrelu(float x) { return x > 0.f ? x : NEG_SLOPE * x; }

typedef _Float16 f16x8 __attribute__((ext_vector_type(8)));
typedef float f32x4 __attribute__((ext_vector_type(4)));

__device__ __forceinline__ unsigned f2u(float a, float b) {
    __half2 h = __float22half2_rn(make_float2(a, b));
    return *(unsigned*)&h;
}

// ---------------------------------------------------------------------------
// K1 (fused): blocks [0,GB) = MFMA GEMM h1=x@W1 (fp16 in, f32 accum) + fused
// alphas (as1 stored fp16, ad1 f32) + fp16 h1 store; blocks [GB,GB+NBLK) =
// bucket histogram -> M[b][blk]. Block 0 zeroes gacc + done-counter.
// GEMM: 64x64 block, 4 waves; mfma_f32_16x16x32_f16, K 2x4 steps. LDS 34.8KB.
// ---------------------------------------------------------------------------
__global__ __launch_bounds__(256) void k_front(
    const float* __restrict__ x, const float* __restrict__ W,
    const float* __restrict__ a_src, const float* __restrict__ a_dst,
    __half* __restrict__ h1h, __half* __restrict__ as1h, float* __restrict__ ad1,
    const int* __restrict__ eidx, unsigned* __restrict__ M,
    float* __restrict__ gacc, unsigned* __restrict__ dcnt,
    int N, int E, int GB, int NB, int CH)
{
    __shared__ unsigned xl2[64][68];   // [row][k-pair uint], 17408 B
    __shared__ unsigned wl2[64][68];   // [col][k-pair uint], 17408 B

    if (blockIdx.x >= GB) {
        // ---- histogram path (aliases xl2) ----
        unsigned* hist = &xl2[0][0];
        for (int i = threadIdx.x; i < NB; i += 256) hist[i] = 0;
        __syncthreads();
        const int blk = blockIdx.x - GB;
        const int lo = blk * CH;
        const int hi = min(lo + CH, E + N);
        for (int i = lo + (int)threadIdx.x; i < hi; i += 256) {
            int d = (i < E) ? eidx[E + i] : (i - E);
            atomicAdd(&hist[d >> 7], 1u);
        }
        __syncthreads();
        for (int b = threadIdx.x; b < NB; b += 256)
            M[(size_t)b * NBLK + blk] = hist[b];
        return;
    }

    // ---- GEMM path ----
    if (blockIdx.x == 0) {
        for (int i = threadIdx.x; i < 1024; i += 256) gacc[i] = 0.f;  // 64 x 16
        if (threadIdx.x == 0) *dcnt = 0u;
    }
    const int t   = threadIdx.x;
    const int lw  = t & 63;        // lane
    const int wv  = t >> 6;        // wave 0..3 -> rows 16wv..16wv+15
    const int row0 = blockIdx.x * 64;

    f32x4 acc[4] = {};             // 4 col-tiles x 4 f32

    for (int kc = 0; kc < NF; kc += 128) {
        if (kc) __syncthreads();
        // stage x tile: 64 rows x 128 k. thread: row t>>2, k-quarter t&3.
        {
            const int r = t >> 2, q = t & 3;
            int row = row0 + r; if (row >= N) row = N - 1;
            const float4* xs = (const float4*)(x + (size_t)row * NF + kc + q * 32);
            #pragma unroll
            for (int i = 0; i < 8; ++i) {
                float4 v = xs[i];
                xl2[r][q * 16 + 2 * i]     = f2u(v.x, v.y);
                xl2[r][q * 16 + 2 * i + 1] = f2u(v.z, v.w);
            }
        }
        // stage W tile TRANSPOSED: thread: col t&63, k-segment t>>6 (32 k's).
        {
            const int c = t & 63, seg = t >> 6;
            #pragma unroll
            for (int m = 0; m < 16; ++m) {
                int k = kc + seg * 32 + 2 * m;
                float w0 = W[(size_t)k * NO + c];
                float w1 = W[(size_t)(k + 1) * NO + c];
                wl2[c][seg * 16 + m] = f2u(w0, w1);
            }
        }
        __syncthreads();

        const int mrow = 16 * wv + (lw & 15);
        const int fcol = (lw >> 4) * 4;       // uint offset of this lane's 8 k's
        #pragma unroll
        for (int ks = 0; ks < 4; ++ks) {
            f16x8 a = *(const f16x8*)&xl2[mrow][ks * 16 + fcol];
            #pragma unroll
            for (int ct = 0; ct < 4; ++ct) {
                f16x8 b = *(const f16x8*)&wl2[16 * ct + (lw & 15)][ks * 16 + fcol];
                acc[ct] = __builtin_amdgcn_mfma_f32_16x16x32_f16(a, b, acc[ct], 0, 0, 0);
            }
        }
    }

    // epilogue: D[m=(lw>>4)*4+j][n=lw&15]; store h1 fp16 + per-head alphas
    const int colb = lw & 15;
    #pragma unroll
    for (int ct = 0; ct < 4; ++ct) {
        const int col = 16 * ct + colb;
        const float asc = a_src[col];
        const float adc = a_dst[col];
        #pragma unroll
        for (int j = 0; j < 4; ++j) {
            const int rowAbs = row0 + 16 * wv + (lw >> 4) * 4 + j;
            float v = acc[ct][j];
            float vs = v * asc, vd = v * adc;
            vs += __shfl_xor(vs, 1); vs += __shfl_xor(vs, 2); vs += __shfl_xor(vs, 4);
            vd += __shfl_xor(vd, 1); vd += __shfl_xor(vd, 2); vd += __shfl_xor(vd, 4);
            if (rowAbs < N) {
                h1h[(size_t)rowAbs * NO + col] = __float2half(v);
                if ((colb & 7) == 0) {
                    int head = 2 * ct + (colb >> 3);
                    as1h[rowAbs * NHEAD + head] = __float2half(vs);
                    ad1[rowAbs * NHEAD + head] = vd;
                }
            }
        }
    }
}

// ---------------------------------------------------------------------------
// K2: single block, 1024 threads. Row-sum M -> totals; serial scan -> Bbase;
// per-row uint4 wave scans -> in-place scatter cursors in M.
// ---------------------------------------------------------------------------
__global__ __launch_bounds__(1024) void k_scan2(
    unsigned* __restrict__ M, unsigned* __restrict__ Bbase, int NB)
{
    __shared__ unsigned tot[512];
    __shared__ unsigned basel[513];
    const int t = threadIdx.x, lane = t & 63, w = t >> 6;  // 16 waves

    for (int b = w; b < NB; b += 16) {
        uint4 v = ((const uint4*)&M[(size_t)b * NBLK])[lane];
        unsigned s = v.x + v.y + v.z + v.w;
        #pragma unroll
        for (int m = 1; m < 64; m <<= 1) s += __shfl_xor(s, m);
        if (lane == 0) tot[b] = s;
    }
    __syncthreads();
    if (t == 0) {
        unsigned r = 0;
        for (int b = 0; b < NB; ++b) { basel[b] = r; r += tot[b]; }
        basel[NB] = r;
    }
    __syncthreads();
    for (int b = t; b <= NB; b += 1024) Bbase[b] = basel[b];
    for (int b = w; b < NB; b += 16) {
        uint4 v = ((const uint4*)&M[(size_t)b * NBLK])[lane];
        unsigned lsum = v.x + v.y + v.z + v.w;
        unsigned p = lsum;
        #pragma unroll
        for (int d = 1; d < 64; d <<= 1) {
            unsigned q = __shfl_up(p, d);
            if (lane >= d) p += q;
        }
        unsigned c0 = basel[b] + p - lsum;
        uint4 o;
        o.x = c0;
        o.y = c0 + v.x;
        o.z = o.y + v.y;
        o.w = o.z + v.z;
        ((uint4*)&M[(size_t)b * NBLK])[lane] = o;
    }
}

// ---------------------------------------------------------------------------
// K3: scatter packed records (s<<7 | d_local) into bucket-contiguous regions.
// ---------------------------------------------------------------------------
__global__ __launch_bounds__(256) void k_bscatter(
    const int* __restrict__ eidx, int E, int N, int NB, int CH,
    const unsigned* __restrict__ M, unsigned* __restrict__ rbuf)
{
    __shared__ unsigned cur[512];
    const int blk = blockIdx.x;
    for (int b = threadIdx.x; b < NB; b += 256)
        cur[b] = M[(size_t)b * NBLK + blk];
    __syncthreads();
    const int lo = blk * CH;
    const int hi = min(lo + CH, E + N);
    for (int i = lo + (int)threadIdx.x; i < hi; i += 256) {
        int s, d;
        if (i < E) { s = eidx[i]; d = eidx[E + i]; }
        else       { s = i - E;   d = i - E; }
        unsigned pos = atomicAdd(&cur[d >> 7], 1u);
        rbuf[pos] = ((unsigned)s << 7) | (unsigned)(d & (BKT - 1));
    }
}

// ---------------------------------------------------------------------------
// K4: per-bucket LDS counting sort -> node-ordered csr (in place) + offs.
// ---------------------------------------------------------------------------
__global__ __launch_bounds__(256) void k_csr(
    const unsigned* __restrict__ Bbase, int N, int NB,
    unsigned* __restrict__ rbuf, unsigned* __restrict__ offs)
{
    __shared__ unsigned recs[RCAP];
    __shared__ unsigned nhist[BKT];
    __shared__ unsigned ncur[BKT];
    __shared__ unsigned wtotS;
    const int b = blockIdx.x;
    const unsigned base = Bbase[b], end = Bbase[b + 1];
    const int cnt = (int)(end - base);
    const int nodes = min(BKT, N - b * BKT);

    for (int i = threadIdx.x; i < BKT; i += 256) nhist[i] = 0;
    __syncthreads();
    for (int i = threadIdx.x; i < cnt; i += 256) {
        unsigned r = rbuf[base + i];
        recs[i] = r;
        atomicAdd(&nhist[r & (BKT - 1)], 1u);
    }
    __syncthreads();
    const int tl = threadIdx.x & 127;
    unsigned v = nhist[tl], p = v;
    #pragma unroll
    for (int d = 1; d < 64; d <<= 1) {
        unsigned q = __shfl_up(p, d);
        if ((tl & 63) >= d) p += q;
    }
    if (threadIdx.x == 63) wtotS = p;
    __syncthreads();
    unsigned excl = base + ((tl >= 64) ? wtotS : 0u) + p - v;
    if (threadIdx.x < 128) {
        ncur[tl] = excl;
        if (tl < nodes) offs[b * BKT + tl] = excl;
    }
    if (b == NB - 1 && threadIdx.x == 0) offs[N] = end;
    __syncthreads();
    for (int i = threadIdx.x; i < cnt; i += 256) {
        unsigned r = recs[i];
        unsigned pos = atomicAdd(&ncur[r & (BKT - 1)], 1u);
        rbuf[pos] = r >> 7;
    }
}

// ---------------------------------------------------------------------------
// K5: layer-1 GAT aggregation. One wave per dst node, 8 lanes/edge
// (slot = lane>>3, head = lane&7), exp/lrelu once per (edge,head),
// 4 edges in flight per lane. as1 fp16 (halves alpha-gather bytes).
// Fused epilogue: relu(acc/den+b1) . W2 -> h2.
// ---------------------------------------------------------------------------
__global__ __launch_bounds__(256) void k_gat1(
    const unsigned* __restrict__ offs, const int* __restrict__ csr,
    const float4* __restrict__ h1q, const __half* __restrict__ as1h,
    const float* __restrict__ ad1,
    const float* __restrict__ b1, const float* __restrict__ W2,
    float* __restrict__ h2, int N)
{
    const int lane = threadIdx.x & 63;
    const int n = blockIdx.x * (blockDim.x >> 6) + (threadIdx.x >> 6);
    if (n >= N) return;
    const int slot = lane >> 3;
    const int head = lane & 7;
    const unsigned s0 = offs[n];
    const unsigned deg = offs[n + 1] - s0;
    const float ad = ad1[n * NHEAD + head];

    float acc[8] = {};
    float den = 0.f;

    unsigned k = (unsigned)slot;
    for (; k + 24 < deg; k += 32) {
        int sA = csr[s0 + k],      sB = csr[s0 + k + 8];
        int sC = csr[s0 + k + 16], sD = csr[s0 + k + 24];
        float aA = __half2float(as1h[sA * NHEAD + head]);
        float aB = __half2float(as1h[sB * NHEAD + head]);
        float aC = __half2float(as1h[sC * NHEAD + head]);
        float aD = __half2float(as1h[sD * NHEAD + head]);
        float4 rA = h1q[(unsigned)sA * 8u + head];
        float4 rB = h1q[(unsigned)sB * 8u + head];
        float4 rC = h1q[(unsigned)sC * 8u + head];
        float4 rD = h1q[(unsigned)sD * 8u + head];
        float pA = __expf(lrelu(aA + ad));
        float pB = __expf(lrelu(aB + ad));
        float pC = __expf(lrelu(aC + ad));
        float pD = __expf(lrelu(aD + ad));
        den += (pA + pB) + (pC + pD);
        const __half2* hA = (const __half2*)&rA;
        const __half2* hB = (const __half2*)&rB;
        const __half2* hC = (const __half2*)&rC;
        const __half2* hD = (const __half2*)&rD;
        #pragma unroll
        for (int j = 0; j < 4; ++j) {
            float2 fA = __half22float2(hA[j]);
            float2 fB = __half22float2(hB[j]);
            float2 fC = __half22float2(hC[j]);
            float2 fD = __half22float2(hD[j]);
            acc[2 * j]     = fmaf(pA, fA.x, acc[2 * j]);
            acc[2 * j + 1] = fmaf(pA, fA.y, acc[2 * j + 1]);
            acc[2 * j]     = fmaf(pB, fB.x, acc[2 * j]);
            acc[2 * j + 1] = fmaf(pB, fB.y, acc[2 * j + 1]);
            acc[2 * j]     = fmaf(pC, fC.x, acc[2 * j]);
            acc[2 * j + 1] = fmaf(pC, fC.y, acc[2 * j + 1]);
            acc[2 * j]     = fmaf(pD, fD.x, acc[2 * j]);
            acc[2 * j + 1] = fmaf(pD, fD.y, acc[2 * j + 1]);
        }
    }
    for (; k + 8 < deg; k += 16) {
        int sA = csr[s0 + k], sB = csr[s0 + k + 8];
        float aA = __half2float(as1h[sA * NHEAD + head]);
        float aB = __half2float(as1h[sB * NHEAD + head]);
        float4 rA = h1q[(unsigned)sA * 8u + head];
        float4 rB = h1q[(unsigned)sB * 8u + head];
        float pA = __expf(lrelu(aA + ad));
        float pB = __expf(lrelu(aB + ad));
        den += pA + pB;
        const __half2* hA = (const __half2*)&rA;
        const __half2* hB = (const __half2*)&rB;
        #pragma unroll
        for (int j = 0; j < 4; ++j) {
            float2 fA = __half22float2(hA[j]);
            float2 fB = __half22float2(hB[j]);
            acc[2 * j]     = fmaf(pA, fA.x, acc[2 * j]);
            acc[2 * j + 1] = fmaf(pA, fA.y, acc[2 * j + 1]);
            acc[2 * j]     = fmaf(pB, fB.x, acc[2 * j]);
            acc[2 * j + 1] = fmaf(pB, fB.y, acc[2 * j + 1]);
        }
    }
    if (k < deg) {
        int s = csr[s0 + k];
        float a = __half2float(as1h[s * NHEAD + head]);
        float4 r = h1q[(unsigned)s * 8u + head];
        float p = __expf(lrelu(a + ad));
        den += p;
        const __half2* hh = (const __half2*)&r;
        #pragma unroll
        for (int j = 0; j < 4; ++j) {
            float2 f = __half22float2(hh[j]);
            acc[2 * j]     = fmaf(p, f.x, acc[2 * j]);
            acc[2 * j + 1] = fmaf(p, f.y, acc[2 * j + 1]);
        }
    }

    #pragma unroll
    for (int r = 0; r < 8; ++r) {
        acc[r] += __shfl_xor(acc[r], 8);
        acc[r] += __shfl_xor(acc[r], 16);
        acc[r] += __shfl_xor(acc[r], 32);
    }
    den += __shfl_xor(den, 8);
    den += __shfl_xor(den, 16);
    den += __shfl_xor(den, 32);

    const float4 b0 = ((const float4*)b1)[head * 2];
    const float4 b1v = ((const float4*)b1)[head * 2 + 1];
    const float4 w0 = ((const float4*)W2)[head * 2];
    const float4 w1v = ((const float4*)W2)[head * 2 + 1];
    const float inv = 1.f / den;
    float tt = 0.f;
    tt += fmaxf(fmaf(acc[0], inv, b0.x), 0.f) * w0.x;
    tt += fmaxf(fmaf(acc[1], inv, b0.y), 0.f) * w0.y;
    tt += fmaxf(fmaf(acc[2], inv, b0.z), 0.f) * w0.z;
    tt += fmaxf(fmaf(acc[3], inv, b0.w), 0.f) * w0.w;
    tt += fmaxf(fmaf(acc[4], inv, b1v.x), 0.f) * w1v.x;
    tt += fmaxf(fmaf(acc[5], inv, b1v.y), 0.f) * w1v.y;
    tt += fmaxf(fmaf(acc[6], inv, b1v.z), 0.f) * w1v.z;
    tt += fmaxf(fmaf(acc[7], inv, b1v.w), 0.f) * w1v.w;
    tt += __shfl_xor(tt, 1);
    tt += __shfl_xor(tt, 2);
    tt += __shfl_xor(tt, 4);
    if (lane == 0) h2[n] = tt;
}

// ---------------------------------------------------------------------------
// K6 (fused): layer-2 GAT + mean-pool accumulate + FINAL MEAN (last block).
// 64 nodes/block, wave-0 segmented reduce, padded gacc atomics. After each
// block's atomics drain (__syncthreads emits vmcnt(0)), thread 0 fences and
// bumps dcnt; the last block reads gacc via returning atomics (coherent)
// and writes the per-graph means — removes the k_final launch.
// ---------------------------------------------------------------------------
__global__ __launch_bounds__(1024) void k_gat2pool(
    const unsigned* __restrict__ offs, const int* __restrict__ csr,
    const float* __restrict__ h2, const int* __restrict__ batch,
    const float* __restrict__ a_src2, const float* __restrict__ a_dst2,
    const float* __restrict__ b2, float* __restrict__ gacc,
    unsigned* __restrict__ dcnt, float* __restrict__ out, int N, int G)
{
    __shared__ float vals[64];
    __shared__ int gid[64];
    __shared__ unsigned lastflag;
    const int t = threadIdx.x;
    if (t < 64) gid[t] = -1;
    __syncthreads();

    const int lane = t & 63;
    const int ql = lane & 15;
    const int slot = (t >> 6) * 4 + (lane >> 4);
    const int n = blockIdx.x * 64 + slot;

    if (n < N) {
        const float aS = a_src2[0], aD = a_dst2[0];
        const unsigned s0 = offs[n], s1 = offs[n + 1];
        const float ad = h2[n] * aD;
        float num = 0.f, den = 0.f;
        for (unsigned j = s0 + (unsigned)ql; j < s1; j += 16) {
            float hs = h2[csr[j]];
            float p = __expf(lrelu(hs * aS + ad));
            num = fmaf(p, hs, num);
            den += p;
        }
        #pragma unroll
        for (int msk = 1; msk < 16; msk <<= 1) {
            num += __shfl_xor(num, msk);
            den += __shfl_xor(den, msk);
        }
        if (ql == 0) {
            vals[slot] = num / den + b2[0];
            gid[slot] = batch[n];
        }
    }
    __syncthreads();

    if (t < 64) {
        int g = gid[t];
        float o = (g >= 0) ? vals[t] : 0.f;
        const int g0 = __shfl(g, 0);
        const bool same = (g == g0);
        float s = same ? o : 0.f;
        float c = (same && g >= 0) ? 1.f : 0.f;
        #pragma unroll
        for (int msk = 1; msk < 64; msk <<= 1) {
            s += __shfl_xor(s, msk);
            c += __shfl_xor(c, msk);
        }
        if (t == 0) {
            unsafeAtomicAdd(&gacc[g0 * 16], s);
            unsafeAtomicAdd(&gacc[g0 * 16 + 1], c);
        }
        if (g >= 0 && !same) {
            unsafeAtomicAdd(&gacc[g * 16], o);
            unsafeAtomicAdd(&gacc[g * 16 + 1], 1.0f);
        }
    }
    // drain this block's atomics (syncthreads waits vmcnt(0)), then count in
    __syncthreads();
    if (t == 0) {
        __threadfence();
        unsigned v = atomicAdd(dcnt, 1u);
        lastflag = (v == gridDim.x - 1) ? 1u : 0u;
    }
    __syncthreads();
    if (lastflag && t < G) {
        float s = unsafeAtomicAdd(&gacc[t * 16], 0.0f);      // coherent read
        float c = unsafeAtomicAdd(&gacc[t * 16 + 1], 0.0f);
        out[t] = s / fmaxf(c, 1.0f);
    }
}

// ---------------------------------------------------------------------------
extern "C" void kernel_launch(void* const* d_in, const int* in_sizes, int n_in,
                              void* d_out, int out_size, void* d_ws, size_t ws_size,
                              hipStream_t stream)
{
    const float* x      = (const float*)d_in[0];
    const int*   eidx   = (const int*)d_in[1];
    const int*   batch  = (const int*)d_in[2];
    const float* W1     = (const float*)d_in[3];
    const float* a_src1 = (const float*)d_in[4];
    const float* a_dst1 = (const float*)d_in[5];
    const float* b1     = (const float*)d_in[6];
    const float* W2     = (const float*)d_in[7];
    const float* a_src2 = (const float*)d_in[8];
    const float* a_dst2 = (const float*)d_in[9];
    const float* b2     = (const float*)d_in[10];

    const int N = in_sizes[0] / NF;      // 50000
    const int E = in_sizes[1] / 2;       // 1600000
    const int G = out_size;              // 64
    const int ETOT = E + N;
    const int NB = (N + BKT - 1) / BKT;  // 391 buckets
    const int CH = (ETOT + NBLK - 1) / NBLK;
    const int GB = (N + 63) / 64;        // 782 gemm blocks

    // workspace layout (bytes)
    char* w = (char*)d_ws;
    __half*   h1h   = (__half*)(w + 0);           //  6,400,000 (fp16)
    __half*   as1h  = (__half*)(w + 6400000);     //    800,000 (fp16)
    float*    ad1   = (float*)(w + 8000000);      //  1,600,000
    float*    h2    = (float*)(w + 9600000);      //    200,000
    unsigned* offs  = (unsigned*)(w + 9800000);   //    200,064
    unsigned* rbuf  = (unsigned*)(w + 10000064);  //  6,600,000 (records -> csr)
    unsigned* M     = (unsigned*)(w + 16600064);  //    400,384 (NB*NBLK)
    unsigned* Bbase = (unsigned*)(w + 17000448);  //      2,048
    float*    gacc  = (float*)(w + 17002496);     //      4,096 (64 graphs x 16)
    unsigned* dcnt  = (unsigned*)(w + 17006592);  //          4

    k_front<<<GB + NBLK, 256, 0, stream>>>(x, W1, a_src1, a_dst1,
                                           h1h, as1h, ad1,
                                           eidx, M, gacc, dcnt, N, E, GB, NB, CH);
    k_scan2<<<1, 1024, 0, stream>>>(M, Bbase, NB);
    k_bscatter<<<NBLK, 256, 0, stream>>>(eidx, E, N, NB, CH, M, rbuf);
    k_csr<<<NB, 256, 0, stream>>>(Bbase, N, NB, rbuf, offs);

    const int* csr = (const int*)rbuf;
    k_gat1<<<(N + 3) / 4, 256, 0, stream>>>(offs, csr, (const float4*)h1h,
                                            as1h, ad1, b1, W2, h2, N);
    k_gat2pool<<<(N + 63) / 64, 1024, 0, stream>>>(offs, csr, h2, batch,
                                                   a_src2, a_dst2, b2, gacc,
                                                   dcnt, (float*)d_out, N, G);
}

// Round 15
// 132.056 us; speedup vs baseline: 1.0669x; 1.0669x over previous
//
#include <hip/hip_runtime.h>
#include <hip/hip_bf16.h>
#include <hip/hip_fp16.h>
#include <math.h>

#define NF 256    // input features
#define NO 64     // heads*c1 = 8*8
#define NHEAD 8
#define NEG_SLOPE 0.2f
#define BKT 128   // nodes per dst-bucket (d>>7); d_local = 7 bits
#define NBLK 256  // edge-chunk blocks for binning
#define RCAP 8192 // LDS record capacity in k_csr

__device__ __forceinline__ float lrelu(float x) { return x > 0.f ? x : NEG_SLOPE * x; }

typedef _Float16 f16x8 __attribute__((ext_vector_type(8)));
typedef float f32x4 __attribute__((ext_vector_type(4)));

__device__ __forceinline__ unsigned f2u(float a, float b) {
    __half2 h = __float22half2_rn(make_float2(a, b));
    return *(unsigned*)&h;
}

// ---------------------------------------------------------------------------
// K1 (fused): blocks [0,GB) = MFMA GEMM h1=x@W1 (fp16 in, f32 accum) + fused
// alphas (as1 fp16, ad1 f32) + fp16 h1 store; blocks [GB,GB+NBLK) = bucket
// histogram -> M[b][blk]. Block 0 zeroes gacc.
// NOTE r14: fusing k_final via per-block __threadfence + done-counter cost
// +8us (782 device-scope fences) — keep k_final as its own launch.
// ---------------------------------------------------------------------------
__global__ __launch_bounds__(256) void k_front(
    const float* __restrict__ x, const float* __restrict__ W,
    const float* __restrict__ a_src, const float* __restrict__ a_dst,
    __half* __restrict__ h1h, __half* __restrict__ as1h, float* __restrict__ ad1,
    const int* __restrict__ eidx, unsigned* __restrict__ M,
    float* __restrict__ gacc, int N, int E, int GB, int NB, int CH)
{
    __shared__ unsigned xl2[64][68];   // [row][k-pair uint], 17408 B
    __shared__ unsigned wl2[64][68];   // [col][k-pair uint], 17408 B

    if (blockIdx.x >= GB) {
        // ---- histogram path (aliases xl2) ----
        unsigned* hist = &xl2[0][0];
        for (int i = threadIdx.x; i < NB; i += 256) hist[i] = 0;
        __syncthreads();
        const int blk = blockIdx.x - GB;
        const int lo = blk * CH;
        const int hi = min(lo + CH, E + N);
        for (int i = lo + (int)threadIdx.x; i < hi; i += 256) {
            int d = (i < E) ? eidx[E + i] : (i - E);
            atomicAdd(&hist[d >> 7], 1u);
        }
        __syncthreads();
        for (int b = threadIdx.x; b < NB; b += 256)
            M[(size_t)b * NBLK + blk] = hist[b];
        return;
    }

    // ---- GEMM path ----
    if (blockIdx.x == 0) {
        for (int i = threadIdx.x; i < 1024; i += 256) gacc[i] = 0.f;  // 64 x 16
    }
    const int t   = threadIdx.x;
    const int lw  = t & 63;        // lane
    const int wv  = t >> 6;        // wave 0..3 -> rows 16wv..16wv+15
    const int row0 = blockIdx.x * 64;

    f32x4 acc[4] = {};             // 4 col-tiles x 4 f32

    for (int kc = 0; kc < NF; kc += 128) {
        if (kc) __syncthreads();
        // stage x tile: 64 rows x 128 k. thread: row t>>2, k-quarter t&3.
        {
            const int r = t >> 2, q = t & 3;
            int row = row0 + r; if (row >= N) row = N - 1;
            const float4* xs = (const float4*)(x + (size_t)row * NF + kc + q * 32);
            #pragma unroll
            for (int i = 0; i < 8; ++i) {
                float4 v = xs[i];
                xl2[r][q * 16 + 2 * i]     = f2u(v.x, v.y);
                xl2[r][q * 16 + 2 * i + 1] = f2u(v.z, v.w);
            }
        }
        // stage W tile TRANSPOSED: thread: col t&63, k-segment t>>6 (32 k's).
        {
            const int c = t & 63, seg = t >> 6;
            #pragma unroll
            for (int m = 0; m < 16; ++m) {
                int k = kc + seg * 32 + 2 * m;
                float w0 = W[(size_t)k * NO + c];
                float w1 = W[(size_t)(k + 1) * NO + c];
                wl2[c][seg * 16 + m] = f2u(w0, w1);
            }
        }
        __syncthreads();

        const int mrow = 16 * wv + (lw & 15);
        const int fcol = (lw >> 4) * 4;       // uint offset of this lane's 8 k's
        #pragma unroll
        for (int ks = 0; ks < 4; ++ks) {
            f16x8 a = *(const f16x8*)&xl2[mrow][ks * 16 + fcol];
            #pragma unroll
            for (int ct = 0; ct < 4; ++ct) {
                f16x8 b = *(const f16x8*)&wl2[16 * ct + (lw & 15)][ks * 16 + fcol];
                acc[ct] = __builtin_amdgcn_mfma_f32_16x16x32_f16(a, b, acc[ct], 0, 0, 0);
            }
        }
    }

    // epilogue: D[m=(lw>>4)*4+j][n=lw&15]; store h1 fp16 + per-head alphas
    const int colb = lw & 15;
    #pragma unroll
    for (int ct = 0; ct < 4; ++ct) {
        const int col = 16 * ct + colb;
        const float asc = a_src[col];
        const float adc = a_dst[col];
        #pragma unroll
        for (int j = 0; j < 4; ++j) {
            const int rowAbs = row0 + 16 * wv + (lw >> 4) * 4 + j;
            float v = acc[ct][j];
            float vs = v * asc, vd = v * adc;
            vs += __shfl_xor(vs, 1); vs += __shfl_xor(vs, 2); vs += __shfl_xor(vs, 4);
            vd += __shfl_xor(vd, 1); vd += __shfl_xor(vd, 2); vd += __shfl_xor(vd, 4);
            if (rowAbs < N) {
                h1h[(size_t)rowAbs * NO + col] = __float2half(v);
                if ((colb & 7) == 0) {
                    int head = 2 * ct + (colb >> 3);
                    as1h[rowAbs * NHEAD + head] = __float2half(vs);
                    ad1[rowAbs * NHEAD + head] = vd;
                }
            }
        }
    }
}

// ---------------------------------------------------------------------------
// K2: single block, 1024 threads. Row-sum M -> totals; serial scan -> Bbase;
// per-row uint4 wave scans -> in-place scatter cursors in M.
// ---------------------------------------------------------------------------
__global__ __launch_bounds__(1024) void k_scan2(
    unsigned* __restrict__ M, unsigned* __restrict__ Bbase, int NB)
{
    __shared__ unsigned tot[512];
    __shared__ unsigned basel[513];
    const int t = threadIdx.x, lane = t & 63, w = t >> 6;  // 16 waves

    for (int b = w; b < NB; b += 16) {
        uint4 v = ((const uint4*)&M[(size_t)b * NBLK])[lane];
        unsigned s = v.x + v.y + v.z + v.w;
        #pragma unroll
        for (int m = 1; m < 64; m <<= 1) s += __shfl_xor(s, m);
        if (lane == 0) tot[b] = s;
    }
    __syncthreads();
    if (t == 0) {
        unsigned r = 0;
        for (int b = 0; b < NB; ++b) { basel[b] = r; r += tot[b]; }
        basel[NB] = r;
    }
    __syncthreads();
    for (int b = t; b <= NB; b += 1024) Bbase[b] = basel[b];
    for (int b = w; b < NB; b += 16) {
        uint4 v = ((const uint4*)&M[(size_t)b * NBLK])[lane];
        unsigned lsum = v.x + v.y + v.z + v.w;
        unsigned p = lsum;
        #pragma unroll
        for (int d = 1; d < 64; d <<= 1) {
            unsigned q = __shfl_up(p, d);
            if (lane >= d) p += q;
        }
        unsigned c0 = basel[b] + p - lsum;
        uint4 o;
        o.x = c0;
        o.y = c0 + v.x;
        o.z = o.y + v.y;
        o.w = o.z + v.z;
        ((uint4*)&M[(size_t)b * NBLK])[lane] = o;
    }
}

// ---------------------------------------------------------------------------
// K3: scatter packed records (s<<7 | d_local) into bucket-contiguous regions.
// ---------------------------------------------------------------------------
__global__ __launch_bounds__(256) void k_bscatter(
    const int* __restrict__ eidx, int E, int N, int NB, int CH,
    const unsigned* __restrict__ M, unsigned* __restrict__ rbuf)
{
    __shared__ unsigned cur[512];
    const int blk = blockIdx.x;
    for (int b = threadIdx.x; b < NB; b += 256)
        cur[b] = M[(size_t)b * NBLK + blk];
    __syncthreads();
    const int lo = blk * CH;
    const int hi = min(lo + CH, E + N);
    for (int i = lo + (int)threadIdx.x; i < hi; i += 256) {
        int s, d;
        if (i < E) { s = eidx[i]; d = eidx[E + i]; }
        else       { s = i - E;   d = i - E; }
        unsigned pos = atomicAdd(&cur[d >> 7], 1u);
        rbuf[pos] = ((unsigned)s << 7) | (unsigned)(d & (BKT - 1));
    }
}

// ---------------------------------------------------------------------------
// K4: per-bucket LDS counting sort -> node-ordered csr (in place) + offs.
// ---------------------------------------------------------------------------
__global__ __launch_bounds__(256) void k_csr(
    const unsigned* __restrict__ Bbase, int N, int NB,
    unsigned* __restrict__ rbuf, unsigned* __restrict__ offs)
{
    __shared__ unsigned recs[RCAP];
    __shared__ unsigned nhist[BKT];
    __shared__ unsigned ncur[BKT];
    __shared__ unsigned wtotS;
    const int b = blockIdx.x;
    const unsigned base = Bbase[b], end = Bbase[b + 1];
    const int cnt = (int)(end - base);
    const int nodes = min(BKT, N - b * BKT);

    for (int i = threadIdx.x; i < BKT; i += 256) nhist[i] = 0;
    __syncthreads();
    for (int i = threadIdx.x; i < cnt; i += 256) {
        unsigned r = rbuf[base + i];
        recs[i] = r;
        atomicAdd(&nhist[r & (BKT - 1)], 1u);
    }
    __syncthreads();
    const int tl = threadIdx.x & 127;
    unsigned v = nhist[tl], p = v;
    #pragma unroll
    for (int d = 1; d < 64; d <<= 1) {
        unsigned q = __shfl_up(p, d);
        if ((tl & 63) >= d) p += q;
    }
    if (threadIdx.x == 63) wtotS = p;
    __syncthreads();
    unsigned excl = base + ((tl >= 64) ? wtotS : 0u) + p - v;
    if (threadIdx.x < 128) {
        ncur[tl] = excl;
        if (tl < nodes) offs[b * BKT + tl] = excl;
    }
    if (b == NB - 1 && threadIdx.x == 0) offs[N] = end;
    __syncthreads();
    for (int i = threadIdx.x; i < cnt; i += 256) {
        unsigned r = recs[i];
        unsigned pos = atomicAdd(&ncur[r & (BKT - 1)], 1u);
        rbuf[pos] = r >> 7;
    }
}

// ---------------------------------------------------------------------------
// K5: layer-1 GAT aggregation. One wave per dst node, 8 lanes/edge
// (slot = lane>>3, head = lane&7), exp/lrelu once per (edge,head),
// 4 edges in flight per lane. as1 fp16. Fused epilogue -> h2.
// ---------------------------------------------------------------------------
__global__ __launch_bounds__(256) void k_gat1(
    const unsigned* __restrict__ offs, const int* __restrict__ csr,
    const float4* __restrict__ h1q, const __half* __restrict__ as1h,
    const float* __restrict__ ad1,
    const float* __restrict__ b1, const float* __restrict__ W2,
    float* __restrict__ h2, int N)
{
    const int lane = threadIdx.x & 63;
    const int n = blockIdx.x * (blockDim.x >> 6) + (threadIdx.x >> 6);
    if (n >= N) return;
    const int slot = lane >> 3;
    const int head = lane & 7;
    const unsigned s0 = offs[n];
    const unsigned deg = offs[n + 1] - s0;
    const float ad = ad1[n * NHEAD + head];

    float acc[8] = {};
    float den = 0.f;

    unsigned k = (unsigned)slot;
    for (; k + 24 < deg; k += 32) {
        int sA = csr[s0 + k],      sB = csr[s0 + k + 8];
        int sC = csr[s0 + k + 16], sD = csr[s0 + k + 24];
        float aA = __half2float(as1h[sA * NHEAD + head]);
        float aB = __half2float(as1h[sB * NHEAD + head]);
        float aC = __half2float(as1h[sC * NHEAD + head]);
        float aD = __half2float(as1h[sD * NHEAD + head]);
        float4 rA = h1q[(unsigned)sA * 8u + head];
        float4 rB = h1q[(unsigned)sB * 8u + head];
        float4 rC = h1q[(unsigned)sC * 8u + head];
        float4 rD = h1q[(unsigned)sD * 8u + head];
        float pA = __expf(lrelu(aA + ad));
        float pB = __expf(lrelu(aB + ad));
        float pC = __expf(lrelu(aC + ad));
        float pD = __expf(lrelu(aD + ad));
        den += (pA + pB) + (pC + pD);
        const __half2* hA = (const __half2*)&rA;
        const __half2* hB = (const __half2*)&rB;
        const __half2* hC = (const __half2*)&rC;
        const __half2* hD = (const __half2*)&rD;
        #pragma unroll
        for (int j = 0; j < 4; ++j) {
            float2 fA = __half22float2(hA[j]);
            float2 fB = __half22float2(hB[j]);
            float2 fC = __half22float2(hC[j]);
            float2 fD = __half22float2(hD[j]);
            acc[2 * j]     = fmaf(pA, fA.x, acc[2 * j]);
            acc[2 * j + 1] = fmaf(pA, fA.y, acc[2 * j + 1]);
            acc[2 * j]     = fmaf(pB, fB.x, acc[2 * j]);
            acc[2 * j + 1] = fmaf(pB, fB.y, acc[2 * j + 1]);
            acc[2 * j]     = fmaf(pC, fC.x, acc[2 * j]);
            acc[2 * j + 1] = fmaf(pC, fC.y, acc[2 * j + 1]);
            acc[2 * j]     = fmaf(pD, fD.x, acc[2 * j]);
            acc[2 * j + 1] = fmaf(pD, fD.y, acc[2 * j + 1]);
        }
    }
    for (; k + 8 < deg; k += 16) {
        int sA = csr[s0 + k], sB = csr[s0 + k + 8];
        float aA = __half2float(as1h[sA * NHEAD + head]);
        float aB = __half2float(as1h[sB * NHEAD + head]);
        float4 rA = h1q[(unsigned)sA * 8u + head];
        float4 rB = h1q[(unsigned)sB * 8u + head];
        float pA = __expf(lrelu(aA + ad));
        float pB = __expf(lrelu(aB + ad));
        den += pA + pB;
        const __half2* hA = (const __half2*)&rA;
        const __half2* hB = (const __half2*)&rB;
        #pragma unroll
        for (int j = 0; j < 4; ++j) {
            float2 fA = __half22float2(hA[j]);
            float2 fB = __half22float2(hB[j]);
            acc[2 * j]     = fmaf(pA, fA.x, acc[2 * j]);
            acc[2 * j + 1] = fmaf(pA, fA.y, acc[2 * j + 1]);
            acc[2 * j]     = fmaf(pB, fB.x, acc[2 * j]);
            acc[2 * j + 1] = fmaf(pB, fB.y, acc[2 * j + 1]);
        }
    }
    if (k < deg) {
        int s = csr[s0 + k];
        float a = __half2float(as1h[s * NHEAD + head]);
        float4 r = h1q[(unsigned)s * 8u + head];
        float p = __expf(lrelu(a + ad));
        den += p;
        const __half2* hh = (const __half2*)&r;
        #pragma unroll
        for (int j = 0; j < 4; ++j) {
            float2 f = __half22float2(hh[j]);
            acc[2 * j]     = fmaf(p, f.x, acc[2 * j]);
            acc[2 * j + 1] = fmaf(p, f.y, acc[2 * j + 1]);
        }
    }

    #pragma unroll
    for (int r = 0; r < 8; ++r) {
        acc[r] += __shfl_xor(acc[r], 8);
        acc[r] += __shfl_xor(acc[r], 16);
        acc[r] += __shfl_xor(acc[r], 32);
    }
    den += __shfl_xor(den, 8);
    den += __shfl_xor(den, 16);
    den += __shfl_xor(den, 32);

    const float4 b0 = ((const float4*)b1)[head * 2];
    const float4 b1v = ((const float4*)b1)[head * 2 + 1];
    const float4 w0 = ((const float4*)W2)[head * 2];
    const float4 w1v = ((const float4*)W2)[head * 2 + 1];
    const float inv = 1.f / den;
    float tt = 0.f;
    tt += fmaxf(fmaf(acc[0], inv, b0.x), 0.f) * w0.x;
    tt += fmaxf(fmaf(acc[1], inv, b0.y), 0.f) * w0.y;
    tt += fmaxf(fmaf(acc[2], inv, b0.z), 0.f) * w0.z;
    tt += fmaxf(fmaf(acc[3], inv, b0.w), 0.f) * w0.w;
    tt += fmaxf(fmaf(acc[4], inv, b1v.x), 0.f) * w1v.x;
    tt += fmaxf(fmaf(acc[5], inv, b1v.y), 0.f) * w1v.y;
    tt += fmaxf(fmaf(acc[6], inv, b1v.z), 0.f) * w1v.z;
    tt += fmaxf(fmaf(acc[7], inv, b1v.w), 0.f) * w1v.w;
    tt += __shfl_xor(tt, 1);
    tt += __shfl_xor(tt, 2);
    tt += __shfl_xor(tt, 4);
    if (lane == 0) h2[n] = tt;
}

// ---------------------------------------------------------------------------
// K6 (fused): layer-2 GAT + mean-pool accumulate, 64 nodes/block,
// wave-0 segmented reduce, padded gacc atomics. (r13 structure — no fence.)
// ---------------------------------------------------------------------------
__global__ __launch_bounds__(1024) void k_gat2pool(
    const unsigned* __restrict__ offs, const int* __restrict__ csr,
    const float* __restrict__ h2, const int* __restrict__ batch,
    const float* __restrict__ a_src2, const float* __restrict__ a_dst2,
    const float* __restrict__ b2, float* __restrict__ gacc, int N)
{
    __shared__ float vals[64];
    __shared__ int gid[64];
    const int t = threadIdx.x;
    if (t < 64) gid[t] = -1;
    __syncthreads();

    const int lane = t & 63;
    const int ql = lane & 15;
    const int slot = (t >> 6) * 4 + (lane >> 4);
    const int n = blockIdx.x * 64 + slot;

    if (n < N) {
        const float aS = a_src2[0], aD = a_dst2[0];
        const unsigned s0 = offs[n], s1 = offs[n + 1];
        const float ad = h2[n] * aD;
        float num = 0.f, den = 0.f;
        for (unsigned j = s0 + (unsigned)ql; j < s1; j += 16) {
            float hs = h2[csr[j]];
            float p = __expf(lrelu(hs * aS + ad));
            num = fmaf(p, hs, num);
            den += p;
        }
        #pragma unroll
        for (int msk = 1; msk < 16; msk <<= 1) {
            num += __shfl_xor(num, msk);
            den += __shfl_xor(den, msk);
        }
        if (ql == 0) {
            vals[slot] = num / den + b2[0];
            gid[slot] = batch[n];
        }
    }
    __syncthreads();

    if (t < 64) {
        int g = gid[t];
        float o = (g >= 0) ? vals[t] : 0.f;
        const int g0 = __shfl(g, 0);
        const bool same = (g == g0);
        float s = same ? o : 0.f;
        float c = (same && g >= 0) ? 1.f : 0.f;
        #pragma unroll
        for (int msk = 1; msk < 64; msk <<= 1) {
            s += __shfl_xor(s, msk);
            c += __shfl_xor(c, msk);
        }
        if (t == 0) {
            unsafeAtomicAdd(&gacc[g0 * 16], s);
            unsafeAtomicAdd(&gacc[g0 * 16 + 1], c);
        }
        if (g >= 0 && !same) {
            unsafeAtomicAdd(&gacc[g * 16], o);
            unsafeAtomicAdd(&gacc[g * 16 + 1], 1.0f);
        }
    }
}

// ---------------------------------------------------------------------------
// K7: final per-graph mean
// ---------------------------------------------------------------------------
__global__ void k_final(const float* __restrict__ gacc,
                        float* __restrict__ out, int G)
{
    int g = blockIdx.x * blockDim.x + threadIdx.x;
    if (g < G) out[g] = gacc[g * 16] / fmaxf(gacc[g * 16 + 1], 1.0f);
}

// ---------------------------------------------------------------------------
extern "C" void kernel_launch(void* const* d_in, const int* in_sizes, int n_in,
                              void* d_out, int out_size, void* d_ws, size_t ws_size,
                              hipStream_t stream)
{
    const float* x      = (const float*)d_in[0];
    const int*   eidx   = (const int*)d_in[1];
    const int*   batch  = (const int*)d_in[2];
    const float* W1     = (const float*)d_in[3];
    const float* a_src1 = (const float*)d_in[4];
    const float* a_dst1 = (const float*)d_in[5];
    const float* b1     = (const float*)d_in[6];
    const float* W2     = (const float*)d_in[7];
    const float* a_src2 = (const float*)d_in[8];
    const float* a_dst2 = (const float*)d_in[9];
    const float* b2     = (const float*)d_in[10];

    const int N = in_sizes[0] / NF;      // 50000
    const int E = in_sizes[1] / 2;       // 1600000
    const int G = out_size;              // 64
    const int ETOT = E + N;
    const int NB = (N + BKT - 1) / BKT;  // 391 buckets
    const int CH = (ETOT + NBLK - 1) / NBLK;
    const int GB = (N + 63) / 64;        // 782 gemm blocks

    // workspace layout (bytes)
    char* w = (char*)d_ws;
    __half*   h1h   = (__half*)(w + 0);           //  6,400,000 (fp16)
    __half*   as1h  = (__half*)(w + 6400000);     //    800,000 (fp16)
    float*    ad1   = (float*)(w + 8000000);      //  1,600,000
    float*    h2    = (float*)(w + 9600000);      //    200,000
    unsigned* offs  = (unsigned*)(w + 9800000);   //    200,064
    unsigned* rbuf  = (unsigned*)(w + 10000064);  //  6,600,000 (records -> csr)
    unsigned* M     = (unsigned*)(w + 16600064);  //    400,384 (NB*NBLK)
    unsigned* Bbase = (unsigned*)(w + 17000448);  //      2,048
    float*    gacc  = (float*)(w + 17002496);     //      4,096 (64 graphs x 16)

    k_front<<<GB + NBLK, 256, 0, stream>>>(x, W1, a_src1, a_dst1,
                                           h1h, as1h, ad1,
                                           eidx, M, gacc, N, E, GB, NB, CH);
    k_scan2<<<1, 1024, 0, stream>>>(M, Bbase, NB);
    k_bscatter<<<NBLK, 256, 0, stream>>>(eidx, E, N, NB, CH, M, rbuf);
    k_csr<<<NB, 256, 0, stream>>>(Bbase, N, NB, rbuf, offs);

    const int* csr = (const int*)rbuf;
    k_gat1<<<(N + 3) / 4, 256, 0, stream>>>(offs, csr, (const float4*)h1h,
                                            as1h, ad1, b1, W2, h2, N);
    k_gat2pool<<<(N + 63) / 64, 1024, 0, stream>>>(offs, csr, h2, batch,
                                                   a_src2, a_dst2, b2, gacc, N);
    k_final<<<1, 64, 0, stream>>>(gacc, (float*)d_out, G);
}